// Round 4
// baseline (147.688 us; speedup 1.0000x reference)
//
#include <hip/hip_runtime.h>
#include <hip/hip_bf16.h>

#define NN  512
#define CC  64
#define HID 256
#define H4  (HID/4)
#define PSTRIDE (NN*HID)
#define PROWS 2
#define NB_BORDER 256            // border blocks, dispatched first

typedef short  bf16x8 __attribute__((ext_vector_type(8)));
typedef float  f32x4  __attribute__((ext_vector_type(4)));

// ---------------------------------------------------------------------------
// Kernel 1: 6 small projections. P slots: [PA,PC,PE,PB,PD,PF], b1 in PA.
// ---------------------------------------------------------------------------
__global__ __launch_bounds__(256) void proj_kernel(
    const float* __restrict__ xl, const float* __restrict__ xr,
    const float* __restrict__ W1, const float* __restrict__ b1,
    float* __restrict__ P)
{
  const int side = blockIdx.y;
  const int i0   = blockIdx.x * PROWS;
  const int h    = threadIdx.x;
  const float* __restrict__ x = side ? xr : xl;

  __shared__ float xs[PROWS][CC];
  if (threadIdx.x < PROWS * CC)
    xs[threadIdx.x >> 6][threadIdx.x & 63] = x[i0 * CC + threadIdx.x];
  __syncthreads();

  float acc0[PROWS], acc1[PROWS], acc2[PROWS];
#pragma unroll
  for (int r = 0; r < PROWS; r++) { acc0[r] = 0.f; acc1[r] = 0.f; acc2[r] = 0.f; }

  const int base = side ? CC : 0;
  const float* __restrict__ w0p = W1 + (base      ) * HID + h;
  const float* __restrict__ w1p = W1 + (base + 128) * HID + h;
  const float* __restrict__ w2p = W1 + (base + 256) * HID + h;
#pragma unroll 8
  for (int c = 0; c < CC; c++) {
    float w0 = w0p[c * HID];
    float w1 = w1p[c * HID];
    float w2 = w2p[c * HID];
#pragma unroll
    for (int r = 0; r < PROWS; r++) {
      float xv = xs[r][c];
      acc0[r] = fmaf(xv, w0, acc0[r]);
      acc1[r] = fmaf(xv, w1, acc1[r]);
      acc2[r] = fmaf(xv, w2, acc2[r]);
    }
  }

  float* __restrict__ O0 = P + (side ? 3 : 0) * PSTRIDE;
  float* __restrict__ O1 = P + (side ? 4 : 1) * PSTRIDE;
  float* __restrict__ O2 = P + (side ? 5 : 2) * PSTRIDE;
  const float bb = side ? 0.f : b1[h];
#pragma unroll
  for (int r = 0; r < PROWS; r++) {
    O0[(i0 + r) * HID + h] = acc0[r] + bb;
    O1[(i0 + r) * HID + h] = acc1[r];
    O2[(i0 + r) * HID + h] = acc2[r];
  }
}

// ---------------------------------------------------------------------------
// Kernel 2: prep. U_i = PA[i]+PC[i-1]+PE[i+1], V_j = PB[j]+PD[j+1]+PF[j-1];
// bf16 copies for MFMA; rowstat = [sumU, sumU2, sumV, sumV2].
// ---------------------------------------------------------------------------
__global__ __launch_bounds__(256) void prep_kernel(
    const float* __restrict__ P,
    float* __restrict__ Uf, float* __restrict__ Vf,
    unsigned short* __restrict__ Ubf, unsigned short* __restrict__ Vbf,
    float* __restrict__ rowstat)
{
  const int r = blockIdx.x, h = threadIdx.x;
  const float* __restrict__ PA = P;
  const float* __restrict__ PC = P + 1 * PSTRIDE;
  const float* __restrict__ PE = P + 2 * PSTRIDE;
  const float* __restrict__ PB = P + 3 * PSTRIDE;
  const float* __restrict__ PD = P + 4 * PSTRIDE;
  const float* __restrict__ PF = P + 5 * PSTRIDE;

  float u = PA[r * HID + h] + PC[(r - 1) * HID + h] + PE[(r + 1) * HID + h];
  float v = PB[r * HID + h] + PD[(r + 1) * HID + h] + PF[(r - 1) * HID + h];
  Uf[r * HID + h] = u;
  Vf[r * HID + h] = v;
  __hip_bfloat16 ub = __float2bfloat16(u), vb = __float2bfloat16(v);
  Ubf[r * HID + h] = *(unsigned short*)&ub;
  Vbf[r * HID + h] = *(unsigned short*)&vb;

  float u2 = u * u, v2 = v * v;
#pragma unroll
  for (int k = 32; k >= 1; k >>= 1) {
    u  += __shfl_xor(u,  k, 64);
    u2 += __shfl_xor(u2, k, 64);
    v  += __shfl_xor(v,  k, 64);
    v2 += __shfl_xor(v2, k, 64);
  }
  __shared__ float red[4][4];
  const int w = h >> 6;
  if ((h & 63) == 0) { red[w][0] = u; red[w][1] = u2; red[w][2] = v; red[w][3] = v2; }
  __syncthreads();
  if (h < 4)
    rowstat[h * NN + r] = red[0][h] + red[1][h] + red[2][h] + red[3][h];
}

// ---------------------------------------------------------------------------
// Kernel 3: Cross[i,j] = sum_h U[i,h]*V[j,h] via bf16 MFMA 16x16x32.
// ---------------------------------------------------------------------------
__global__ __launch_bounds__(256) void cross_kernel(
    const unsigned short* __restrict__ Ubf,
    const unsigned short* __restrict__ Vbf,
    float* __restrict__ Cross)
{
  const int wave = threadIdx.x >> 6, lane = threadIdx.x & 63;
  const int t  = blockIdx.x * 4 + wave;
  const int ti = t >> 5, tj = t & 31;
  const int i0 = ti * 16, j0 = tj * 16;
  const int rc = lane & 15, kb = (lane >> 4) * 8;

  f32x4 acc = {0.f, 0.f, 0.f, 0.f};
#pragma unroll
  for (int k = 0; k < HID; k += 32) {
    bf16x8 a = *(const bf16x8*)(Ubf + (size_t)(i0 + rc) * HID + k + kb);
    bf16x8 b = *(const bf16x8*)(Vbf + (size_t)(j0 + rc) * HID + k + kb);
    acc = __builtin_amdgcn_mfma_f32_16x16x32_bf16(a, b, acc, 0, 0, 0);
  }
  const int orow = (lane >> 4) * 4, ocol = lane & 15;
#pragma unroll
  for (int r = 0; r < 4; r++)
    Cross[(size_t)(i0 + orow + r) * NN + j0 + ocol] = acc[r];
}

__device__ __forceinline__ float celu1(float x) {
  float e = __expf(x) - 1.f;
  return x > 0.f ? x : e;            // cmp + cndmask
}

// ---------------------------------------------------------------------------
// Kernel 4: pair epilogue.
// Blocks [0, NB_BORDER): 2044 border pairs, 2 pairs/wave (overlaps interior).
// Blocks [NB_BORDER, NB_BORDER+2040): interior rows i=1..510, 16 lanes/pair,
// 4 pairs/wave/iter, m=0..7. racc split into 4 accumulators (short chains).
// ---------------------------------------------------------------------------
__global__ __launch_bounds__(256, 6) void pair_kernel(
    const float* __restrict__ P,
    const float* __restrict__ Uf, const float* __restrict__ Vf,
    const float* __restrict__ Cross, const float* __restrict__ rowstat,
    const float* __restrict__ gamma, const float* __restrict__ beta,
    const float* __restrict__ W2, const float* __restrict__ b2,
    float* __restrict__ out)
{
  const int wave = threadIdx.x >> 6, lane = threadIdx.x & 63;
  const float b2s = b2[0];

  if (blockIdx.x >= NB_BORDER) {
    const int bx    = blockIdx.x - NB_BORDER;
    const int i     = 1 + (bx >> 2);            // 1..510
    const int chunk = bx & 3;
    const int g = lane >> 4, q = lane & 15;

    const float4* U4 = (const float4*)(Uf + i * HID + q * 16);
    const float4 u0 = U4[0], u1 = U4[1], u2 = U4[2], u3 = U4[3];
    const float4* G4 = (const float4*)(gamma + q * 16);
    const float4 ga0 = G4[0], ga1 = G4[1], ga2 = G4[2], ga3 = G4[3];
    const float4* B4 = (const float4*)(beta + q * 16);
    const float4 bt0 = B4[0], bt1 = B4[1], bt2 = B4[2], bt3 = B4[3];
    const float4* W4 = (const float4*)(W2 + q * 16);
    const float4 w0 = W4[0], w1 = W4[1], w2 = W4[2], w3 = W4[3];

    const float sUi  = rowstat[0 * NN + i];
    const float sU2i = rowstat[1 * NN + i];
    const float* __restrict__ sV  = rowstat + 2 * NN;
    const float* __restrict__ sV2 = rowstat + 3 * NN;

    const int jbase = 1 + chunk * 128 + wave * 32 + g;
#pragma unroll 2
    for (int m = 0; m < 8; m++) {
      const int j  = jbase + m * 4;
      const int jc = j <= 510 ? j : 510;        // clamp; result discarded
      const float4* V4 = (const float4*)(Vf + jc * HID + q * 16);
      const float4 v0 = V4[0], v1 = V4[1], v2 = V4[2], v3 = V4[3];
      const float Cr = Cross[i * NN + jc];
      const float mu = (sUi + sV[jc]) * (1.f / HID);
      const float t  = fmaf(2.f, Cr, sU2i + sV2[jc]) * (1.f / HID);
      const float rs = rsqrtf(t - mu * mu + 1e-5f);
      const float mrs = -mu * rs;

      auto doh = [&](float& acc, float U, float V, float G, float Bt, float W) {
        float s = U + V;
        float n = fmaf(fmaf(s, rs, mrs), G, Bt);
        acc = fmaf(celu1(n), W, acc);
      };
      float r0 = 0.f, r1 = 0.f, r2 = 0.f, r3 = 0.f;   // 4 indep chains
      doh(r0, u0.x, v0.x, ga0.x, bt0.x, w0.x);
      doh(r0, u0.y, v0.y, ga0.y, bt0.y, w0.y);
      doh(r0, u0.z, v0.z, ga0.z, bt0.z, w0.z);
      doh(r0, u0.w, v0.w, ga0.w, bt0.w, w0.w);
      doh(r1, u1.x, v1.x, ga1.x, bt1.x, w1.x);
      doh(r1, u1.y, v1.y, ga1.y, bt1.y, w1.y);
      doh(r1, u1.z, v1.z, ga1.z, bt1.z, w1.z);
      doh(r1, u1.w, v1.w, ga1.w, bt1.w, w1.w);
      doh(r2, u2.x, v2.x, ga2.x, bt2.x, w2.x);
      doh(r2, u2.y, v2.y, ga2.y, bt2.y, w2.y);
      doh(r2, u2.z, v2.z, ga2.z, bt2.z, w2.z);
      doh(r2, u2.w, v2.w, ga2.w, bt2.w, w2.w);
      doh(r3, u3.x, v3.x, ga3.x, bt3.x, w3.x);
      doh(r3, u3.y, v3.y, ga3.y, bt3.y, w3.y);
      doh(r3, u3.z, v3.z, ga3.z, bt3.z, w3.z);
      doh(r3, u3.w, v3.w, ga3.w, bt3.w, w3.w);
      float racc = (r0 + r1) + (r2 + r3);

#pragma unroll
      for (int k = 1; k <= 8; k <<= 1)
        racc += __shfl_xor(racc, k, 64);
      if (q == 0 && j <= 510)
        out[i * NN + j] = racc + b2s;
    }
  } else {
    // ---- border: 2044 pairs spread over 1024 waves (2 pairs each)
    const int gw = blockIdx.x * 4 + wave;            // 0..1023
    const float4* P4 = (const float4*)P;
    const float4* PA = P4 + 0 * (PSTRIDE / 4);
    const float4* PC = P4 + 1 * (PSTRIDE / 4);
    const float4* PE = P4 + 2 * (PSTRIDE / 4);
    const float4* PB = P4 + 3 * (PSTRIDE / 4);
    const float4* PD = P4 + 4 * (PSTRIDE / 4);
    const float4* PF = P4 + 5 * (PSTRIDE / 4);
    const float4 g  = ((const float4*)gamma)[lane];
    const float4 be = ((const float4*)beta)[lane];
    const float4 w2 = ((const float4*)W2)[lane];

#pragma unroll
    for (int tt = 0; tt < 2; tt++) {
      const int p = gw * 2 + tt;
      if (p >= 2044) break;
      int i, j;
      if      (p < 512)  { i = 0;        j = p;        }
      else if (p < 1024) { i = 511;      j = p - 512;  }
      else if (p < 1534) { i = p - 1023; j = 0;        }
      else               { i = p - 1533; j = 511;      }

      const float4 a  = PA[i * H4 + lane];
      const float4 cu = PC[(i - 1) * H4 + lane];
      const float4 ed = PE[(i + 1) * H4 + lane];
      const float4 b  = PB[j * H4 + lane];
      const float4 du = PD[(j + 1) * H4 + lane];
      const float4 fd = PF[(j - 1) * H4 + lane];
      const float mu_m = (i >= 1 && j <= NN - 2) ? 1.f : 0.f;
      const float md_m = (i <= NN - 2 && j >= 1) ? 1.f : 0.f;

      float s0 = fmaf(md_m, ed.x + fd.x, fmaf(mu_m, cu.x + du.x, a.x + b.x));
      float s1 = fmaf(md_m, ed.y + fd.y, fmaf(mu_m, cu.y + du.y, a.y + b.y));
      float s2 = fmaf(md_m, ed.z + fd.z, fmaf(mu_m, cu.z + du.z, a.z + b.z));
      float s3 = fmaf(md_m, ed.w + fd.w, fmaf(mu_m, cu.w + du.w, a.w + b.w));

      float sum = (s0 + s1) + (s2 + s3);
      float ssq = fmaf(s0, s0, fmaf(s1, s1, fmaf(s2, s2, s3 * s3)));
#pragma unroll
      for (int off = 32; off >= 1; off >>= 1) {
        sum += __shfl_xor(sum, off, 64);
        ssq += __shfl_xor(ssq, off, 64);
      }
      const float mu  = sum * (1.f / HID);
      const float var = fmaf(ssq, 1.f / HID, -mu * mu);
      const float rs  = rsqrtf(var + 1e-5f);
      const float mrs = -mu * rs;

      auto nrm = [&](float s, float G, float Bt) {
        return fmaf(fmaf(s, rs, mrs), G, Bt);
      };
      float racc = fmaf(celu1(nrm(s0, g.x, be.x)), w2.x,
                   fmaf(celu1(nrm(s1, g.y, be.y)), w2.y,
                   fmaf(celu1(nrm(s2, g.z, be.z)), w2.z,
                        celu1(nrm(s3, g.w, be.w)) * w2.w)));
#pragma unroll
      for (int off = 32; off >= 1; off >>= 1)
        racc += __shfl_xor(racc, off, 64);
      if (lane == 0) out[i * NN + j] = racc + b2s;
    }
  }
}

extern "C" void kernel_launch(void* const* d_in, const int* in_sizes, int n_in,
                              void* d_out, int out_size, void* d_ws, size_t ws_size,
                              hipStream_t stream)
{
  const float* xl    = (const float*)d_in[0];
  const float* xr    = (const float*)d_in[1];
  const float* W1    = (const float*)d_in[2];
  const float* b1    = (const float*)d_in[3];
  const float* gamma = (const float*)d_in[4];
  const float* beta  = (const float*)d_in[5];
  const float* W2    = (const float*)d_in[6];
  const float* b2    = (const float*)d_in[7];
  float* out = (float*)d_out;

  float* P     = (float*)d_ws;
  float* Uf    = P + 6 * PSTRIDE;
  float* Vf    = Uf + NN * HID;
  float* Cross = Vf + NN * HID;
  unsigned short* Ubf = (unsigned short*)(Cross + NN * NN);
  unsigned short* Vbf = Ubf + NN * HID;
  float* rowstat = (float*)(Vbf + NN * HID);

  proj_kernel<<<dim3(NN / PROWS, 2), 256, 0, stream>>>(xl, xr, W1, b1, P);
  prep_kernel<<<NN, 256, 0, stream>>>(P, Uf, Vf, Ubf, Vbf, rowstat);
  cross_kernel<<<256, 256, 0, stream>>>(Ubf, Vbf, Cross);
  pair_kernel<<<NB_BORDER + 2040, 256, 0, stream>>>(P, Uf, Vf, Cross, rowstat,
                                                    gamma, beta, W2, b2, out);
}

// Round 5
// 112.470 us; speedup vs baseline: 1.3131x; 1.3131x over previous
//
#include <hip/hip_runtime.h>
#include <hip/hip_bf16.h>

#define NN  512
#define CC  64
#define HID 256
#define H4  (HID/4)
#define PSTRIDE (NN*HID)
#define PROWS 2
#define NB_BORDER 256            // border blocks, dispatched first

typedef short  bf16x8 __attribute__((ext_vector_type(8)));
typedef float  f32x4  __attribute__((ext_vector_type(4)));

// ---------------------------------------------------------------------------
// Kernel 1: 6 small projections. P slots: [PA,PC,PE,PB,PD,PF], b1 in PA.
// ---------------------------------------------------------------------------
__global__ __launch_bounds__(256) void proj_kernel(
    const float* __restrict__ xl, const float* __restrict__ xr,
    const float* __restrict__ W1, const float* __restrict__ b1,
    float* __restrict__ P)
{
  const int side = blockIdx.y;
  const int i0   = blockIdx.x * PROWS;
  const int h    = threadIdx.x;
  const float* __restrict__ x = side ? xr : xl;

  __shared__ float xs[PROWS][CC];
  if (threadIdx.x < PROWS * CC)
    xs[threadIdx.x >> 6][threadIdx.x & 63] = x[i0 * CC + threadIdx.x];
  __syncthreads();

  float acc0[PROWS], acc1[PROWS], acc2[PROWS];
#pragma unroll
  for (int r = 0; r < PROWS; r++) { acc0[r] = 0.f; acc1[r] = 0.f; acc2[r] = 0.f; }

  const int base = side ? CC : 0;
  const float* __restrict__ w0p = W1 + (base      ) * HID + h;
  const float* __restrict__ w1p = W1 + (base + 128) * HID + h;
  const float* __restrict__ w2p = W1 + (base + 256) * HID + h;
#pragma unroll 8
  for (int c = 0; c < CC; c++) {
    float w0 = w0p[c * HID];
    float w1 = w1p[c * HID];
    float w2 = w2p[c * HID];
#pragma unroll
    for (int r = 0; r < PROWS; r++) {
      float xv = xs[r][c];
      acc0[r] = fmaf(xv, w0, acc0[r]);
      acc1[r] = fmaf(xv, w1, acc1[r]);
      acc2[r] = fmaf(xv, w2, acc2[r]);
    }
  }

  float* __restrict__ O0 = P + (side ? 3 : 0) * PSTRIDE;
  float* __restrict__ O1 = P + (side ? 4 : 1) * PSTRIDE;
  float* __restrict__ O2 = P + (side ? 5 : 2) * PSTRIDE;
  const float bb = side ? 0.f : b1[h];
#pragma unroll
  for (int r = 0; r < PROWS; r++) {
    O0[(i0 + r) * HID + h] = acc0[r] + bb;
    O1[(i0 + r) * HID + h] = acc1[r];
    O2[(i0 + r) * HID + h] = acc2[r];
  }
}

// ---------------------------------------------------------------------------
// Kernel 2: prep. U_i = PA[i]+PC[i-1]+PE[i+1], V_j = PB[j]+PD[j+1]+PF[j-1];
// bf16 copies for MFMA; rowstat = [sumU, sumU2, sumV, sumV2].
// ---------------------------------------------------------------------------
__global__ __launch_bounds__(256) void prep_kernel(
    const float* __restrict__ P,
    float* __restrict__ Uf, float* __restrict__ Vf,
    unsigned short* __restrict__ Ubf, unsigned short* __restrict__ Vbf,
    float* __restrict__ rowstat)
{
  const int r = blockIdx.x, h = threadIdx.x;
  const float* __restrict__ PA = P;
  const float* __restrict__ PC = P + 1 * PSTRIDE;
  const float* __restrict__ PE = P + 2 * PSTRIDE;
  const float* __restrict__ PB = P + 3 * PSTRIDE;
  const float* __restrict__ PD = P + 4 * PSTRIDE;
  const float* __restrict__ PF = P + 5 * PSTRIDE;

  float u = PA[r * HID + h] + PC[(r - 1) * HID + h] + PE[(r + 1) * HID + h];
  float v = PB[r * HID + h] + PD[(r + 1) * HID + h] + PF[(r - 1) * HID + h];
  Uf[r * HID + h] = u;
  Vf[r * HID + h] = v;
  __hip_bfloat16 ub = __float2bfloat16(u), vb = __float2bfloat16(v);
  Ubf[r * HID + h] = *(unsigned short*)&ub;
  Vbf[r * HID + h] = *(unsigned short*)&vb;

  float u2 = u * u, v2 = v * v;
#pragma unroll
  for (int k = 32; k >= 1; k >>= 1) {
    u  += __shfl_xor(u,  k, 64);
    u2 += __shfl_xor(u2, k, 64);
    v  += __shfl_xor(v,  k, 64);
    v2 += __shfl_xor(v2, k, 64);
  }
  __shared__ float red[4][4];
  const int w = h >> 6;
  if ((h & 63) == 0) { red[w][0] = u; red[w][1] = u2; red[w][2] = v; red[w][3] = v2; }
  __syncthreads();
  if (h < 4)
    rowstat[h * NN + r] = red[0][h] + red[1][h] + red[2][h] + red[3][h];
}

// ---------------------------------------------------------------------------
// Kernel 3: Cross[i,j] = sum_h U[i,h]*V[j,h] via bf16 MFMA 16x16x32.
// ---------------------------------------------------------------------------
__global__ __launch_bounds__(256) void cross_kernel(
    const unsigned short* __restrict__ Ubf,
    const unsigned short* __restrict__ Vbf,
    float* __restrict__ Cross)
{
  const int wave = threadIdx.x >> 6, lane = threadIdx.x & 63;
  const int t  = blockIdx.x * 4 + wave;
  const int ti = t >> 5, tj = t & 31;
  const int i0 = ti * 16, j0 = tj * 16;
  const int rc = lane & 15, kb = (lane >> 4) * 8;

  f32x4 acc = {0.f, 0.f, 0.f, 0.f};
#pragma unroll
  for (int k = 0; k < HID; k += 32) {
    bf16x8 a = *(const bf16x8*)(Ubf + (size_t)(i0 + rc) * HID + k + kb);
    bf16x8 b = *(const bf16x8*)(Vbf + (size_t)(j0 + rc) * HID + k + kb);
    acc = __builtin_amdgcn_mfma_f32_16x16x32_bf16(a, b, acc, 0, 0, 0);
  }
  const int orow = (lane >> 4) * 4, ocol = lane & 15;
#pragma unroll
  for (int r = 0; r < 4; r++)
    Cross[(size_t)(i0 + orow + r) * NN + j0 + ocol] = acc[r];
}

__device__ __forceinline__ float celu1(float x) {
  float e = __expf(x) - 1.f;
  return x > 0.f ? x : e;            // cmp + cndmask
}

// ---------------------------------------------------------------------------
// Kernel 4: pair epilogue.
// Blocks [0, NB_BORDER): 2044 border pairs, 2 pairs/wave (overlaps interior).
// Blocks [NB_BORDER, ...): interior rows i=1..510, 16 lanes/pair, 4 pairs/wave
// per iter, m=0..7, unroll 2. racc split into 4 accumulators.
// NOTE: plain __launch_bounds__(256) — the (256,6) clamp in R4 forced 40 VGPRs
// and spilled ~90 MB/launch to scratch (WRITE_SIZE 1->44 MB). Let VGPR float.
// ---------------------------------------------------------------------------
__global__ __launch_bounds__(256) void pair_kernel(
    const float* __restrict__ P,
    const float* __restrict__ Uf, const float* __restrict__ Vf,
    const float* __restrict__ Cross, const float* __restrict__ rowstat,
    const float* __restrict__ gamma, const float* __restrict__ beta,
    const float* __restrict__ W2, const float* __restrict__ b2,
    float* __restrict__ out)
{
  const int wave = threadIdx.x >> 6, lane = threadIdx.x & 63;
  const float b2s = b2[0];

  if (blockIdx.x >= NB_BORDER) {
    const int bx    = blockIdx.x - NB_BORDER;
    const int i     = 1 + (bx >> 2);            // 1..510
    const int chunk = bx & 3;
    const int g = lane >> 4, q = lane & 15;

    const float4* U4 = (const float4*)(Uf + i * HID + q * 16);
    const float4 u0 = U4[0], u1 = U4[1], u2 = U4[2], u3 = U4[3];
    const float4* G4 = (const float4*)(gamma + q * 16);
    const float4 ga0 = G4[0], ga1 = G4[1], ga2 = G4[2], ga3 = G4[3];
    const float4* B4 = (const float4*)(beta + q * 16);
    const float4 bt0 = B4[0], bt1 = B4[1], bt2 = B4[2], bt3 = B4[3];
    const float4* W4 = (const float4*)(W2 + q * 16);
    const float4 w0 = W4[0], w1 = W4[1], w2 = W4[2], w3 = W4[3];

    const float sUi  = rowstat[0 * NN + i];
    const float sU2i = rowstat[1 * NN + i];
    const float* __restrict__ sV  = rowstat + 2 * NN;
    const float* __restrict__ sV2 = rowstat + 3 * NN;

    const int jbase = 1 + chunk * 128 + wave * 32 + g;
#pragma unroll 2
    for (int m = 0; m < 8; m++) {
      const int j  = jbase + m * 4;
      const int jc = j <= 510 ? j : 510;        // clamp; result discarded
      const float4* V4 = (const float4*)(Vf + jc * HID + q * 16);
      const float4 v0 = V4[0], v1 = V4[1], v2 = V4[2], v3 = V4[3];
      const float Cr = Cross[i * NN + jc];
      const float mu = (sUi + sV[jc]) * (1.f / HID);
      const float t  = fmaf(2.f, Cr, sU2i + sV2[jc]) * (1.f / HID);
      const float rs = rsqrtf(t - mu * mu + 1e-5f);
      const float mrs = -mu * rs;

      auto doh = [&](float& acc, float U, float V, float G, float Bt, float W) {
        float s = U + V;
        float n = fmaf(fmaf(s, rs, mrs), G, Bt);
        acc = fmaf(celu1(n), W, acc);
      };
      float r0 = 0.f, r1 = 0.f, r2 = 0.f, r3 = 0.f;   // 4 indep chains
      doh(r0, u0.x, v0.x, ga0.x, bt0.x, w0.x);
      doh(r0, u0.y, v0.y, ga0.y, bt0.y, w0.y);
      doh(r0, u0.z, v0.z, ga0.z, bt0.z, w0.z);
      doh(r0, u0.w, v0.w, ga0.w, bt0.w, w0.w);
      doh(r1, u1.x, v1.x, ga1.x, bt1.x, w1.x);
      doh(r1, u1.y, v1.y, ga1.y, bt1.y, w1.y);
      doh(r1, u1.z, v1.z, ga1.z, bt1.z, w1.z);
      doh(r1, u1.w, v1.w, ga1.w, bt1.w, w1.w);
      doh(r2, u2.x, v2.x, ga2.x, bt2.x, w2.x);
      doh(r2, u2.y, v2.y, ga2.y, bt2.y, w2.y);
      doh(r2, u2.z, v2.z, ga2.z, bt2.z, w2.z);
      doh(r2, u2.w, v2.w, ga2.w, bt2.w, w2.w);
      doh(r3, u3.x, v3.x, ga3.x, bt3.x, w3.x);
      doh(r3, u3.y, v3.y, ga3.y, bt3.y, w3.y);
      doh(r3, u3.z, v3.z, ga3.z, bt3.z, w3.z);
      doh(r3, u3.w, v3.w, ga3.w, bt3.w, w3.w);
      float racc = (r0 + r1) + (r2 + r3);

#pragma unroll
      for (int k = 1; k <= 8; k <<= 1)
        racc += __shfl_xor(racc, k, 64);
      if (q == 0 && j <= 510)
        out[i * NN + j] = racc + b2s;
    }
  } else {
    // ---- border: 2044 pairs spread over 1024 waves (2 pairs each)
    const int gw = blockIdx.x * 4 + wave;            // 0..1023
    const float4* P4 = (const float4*)P;
    const float4* PA = P4 + 0 * (PSTRIDE / 4);
    const float4* PC = P4 + 1 * (PSTRIDE / 4);
    const float4* PE = P4 + 2 * (PSTRIDE / 4);
    const float4* PB = P4 + 3 * (PSTRIDE / 4);
    const float4* PD = P4 + 4 * (PSTRIDE / 4);
    const float4* PF = P4 + 5 * (PSTRIDE / 4);
    const float4 g  = ((const float4*)gamma)[lane];
    const float4 be = ((const float4*)beta)[lane];
    const float4 w2 = ((const float4*)W2)[lane];

#pragma unroll
    for (int tt = 0; tt < 2; tt++) {
      const int p = gw * 2 + tt;
      if (p >= 2044) break;
      int i, j;
      if      (p < 512)  { i = 0;        j = p;        }
      else if (p < 1024) { i = 511;      j = p - 512;  }
      else if (p < 1534) { i = p - 1023; j = 0;        }
      else               { i = p - 1533; j = 511;      }

      const float4 a  = PA[i * H4 + lane];
      const float4 cu = PC[(i - 1) * H4 + lane];
      const float4 ed = PE[(i + 1) * H4 + lane];
      const float4 b  = PB[j * H4 + lane];
      const float4 du = PD[(j + 1) * H4 + lane];
      const float4 fd = PF[(j - 1) * H4 + lane];
      const float mu_m = (i >= 1 && j <= NN - 2) ? 1.f : 0.f;
      const float md_m = (i <= NN - 2 && j >= 1) ? 1.f : 0.f;

      float s0 = fmaf(md_m, ed.x + fd.x, fmaf(mu_m, cu.x + du.x, a.x + b.x));
      float s1 = fmaf(md_m, ed.y + fd.y, fmaf(mu_m, cu.y + du.y, a.y + b.y));
      float s2 = fmaf(md_m, ed.z + fd.z, fmaf(mu_m, cu.z + du.z, a.z + b.z));
      float s3 = fmaf(md_m, ed.w + fd.w, fmaf(mu_m, cu.w + du.w, a.w + b.w));

      float sum = (s0 + s1) + (s2 + s3);
      float ssq = fmaf(s0, s0, fmaf(s1, s1, fmaf(s2, s2, s3 * s3)));
#pragma unroll
      for (int off = 32; off >= 1; off >>= 1) {
        sum += __shfl_xor(sum, off, 64);
        ssq += __shfl_xor(ssq, off, 64);
      }
      const float mu  = sum * (1.f / HID);
      const float var = fmaf(ssq, 1.f / HID, -mu * mu);
      const float rs  = rsqrtf(var + 1e-5f);
      const float mrs = -mu * rs;

      auto nrm = [&](float s, float G, float Bt) {
        return fmaf(fmaf(s, rs, mrs), G, Bt);
      };
      float racc = fmaf(celu1(nrm(s0, g.x, be.x)), w2.x,
                   fmaf(celu1(nrm(s1, g.y, be.y)), w2.y,
                   fmaf(celu1(nrm(s2, g.z, be.z)), w2.z,
                        celu1(nrm(s3, g.w, be.w)) * w2.w)));
#pragma unroll
      for (int off = 32; off >= 1; off >>= 1)
        racc += __shfl_xor(racc, off, 64);
      if (lane == 0) out[i * NN + j] = racc + b2s;
    }
  }
}

extern "C" void kernel_launch(void* const* d_in, const int* in_sizes, int n_in,
                              void* d_out, int out_size, void* d_ws, size_t ws_size,
                              hipStream_t stream)
{
  const float* xl    = (const float*)d_in[0];
  const float* xr    = (const float*)d_in[1];
  const float* W1    = (const float*)d_in[2];
  const float* b1    = (const float*)d_in[3];
  const float* gamma = (const float*)d_in[4];
  const float* beta  = (const float*)d_in[5];
  const float* W2    = (const float*)d_in[6];
  const float* b2    = (const float*)d_in[7];
  float* out = (float*)d_out;

  float* P     = (float*)d_ws;
  float* Uf    = P + 6 * PSTRIDE;
  float* Vf    = Uf + NN * HID;
  float* Cross = Vf + NN * HID;
  unsigned short* Ubf = (unsigned short*)(Cross + NN * NN);
  unsigned short* Vbf = Ubf + NN * HID;
  float* rowstat = (float*)(Vbf + NN * HID);

  proj_kernel<<<dim3(NN / PROWS, 2), 256, 0, stream>>>(xl, xr, W1, b1, P);
  prep_kernel<<<NN, 256, 0, stream>>>(P, Uf, Vf, Ubf, Vbf, rowstat);
  cross_kernel<<<256, 256, 0, stream>>>(Ubf, Vbf, Cross);
  pair_kernel<<<NB_BORDER + 2040, 256, 0, stream>>>(P, Uf, Vf, Cross, rowstat,
                                                    gamma, beta, W2, b2, out);
}

// Round 6
// 108.124 us; speedup vs baseline: 1.3659x; 1.0402x over previous
//
#include <hip/hip_runtime.h>
#include <hip/hip_bf16.h>

#define NN  512
#define CC  64
#define HID 256
#define H4  (HID/4)
#define PSTRIDE (NN*HID)
#define PROWS 2
#define NB_BORDER 256            // border blocks, dispatched first

typedef short  bf16x8 __attribute__((ext_vector_type(8)));
typedef float  f32x4  __attribute__((ext_vector_type(4)));

// ---------------------------------------------------------------------------
// Kernel 1: 6 small projections. P slots: [PA,PC,PE,PB,PD,PF], b1 in PA.
// ---------------------------------------------------------------------------
__global__ __launch_bounds__(256) void proj_kernel(
    const float* __restrict__ xl, const float* __restrict__ xr,
    const float* __restrict__ W1, const float* __restrict__ b1,
    float* __restrict__ P)
{
  const int side = blockIdx.y;
  const int i0   = blockIdx.x * PROWS;
  const int h    = threadIdx.x;
  const float* __restrict__ x = side ? xr : xl;

  __shared__ float xs[PROWS][CC];
  if (threadIdx.x < PROWS * CC)
    xs[threadIdx.x >> 6][threadIdx.x & 63] = x[i0 * CC + threadIdx.x];
  __syncthreads();

  float acc0[PROWS], acc1[PROWS], acc2[PROWS];
#pragma unroll
  for (int r = 0; r < PROWS; r++) { acc0[r] = 0.f; acc1[r] = 0.f; acc2[r] = 0.f; }

  const int base = side ? CC : 0;
  const float* __restrict__ w0p = W1 + (base      ) * HID + h;
  const float* __restrict__ w1p = W1 + (base + 128) * HID + h;
  const float* __restrict__ w2p = W1 + (base + 256) * HID + h;
#pragma unroll 8
  for (int c = 0; c < CC; c++) {
    float w0 = w0p[c * HID];
    float w1 = w1p[c * HID];
    float w2 = w2p[c * HID];
#pragma unroll
    for (int r = 0; r < PROWS; r++) {
      float xv = xs[r][c];
      acc0[r] = fmaf(xv, w0, acc0[r]);
      acc1[r] = fmaf(xv, w1, acc1[r]);
      acc2[r] = fmaf(xv, w2, acc2[r]);
    }
  }

  float* __restrict__ O0 = P + (side ? 3 : 0) * PSTRIDE;
  float* __restrict__ O1 = P + (side ? 4 : 1) * PSTRIDE;
  float* __restrict__ O2 = P + (side ? 5 : 2) * PSTRIDE;
  const float bb = side ? 0.f : b1[h];
#pragma unroll
  for (int r = 0; r < PROWS; r++) {
    O0[(i0 + r) * HID + h] = acc0[r] + bb;
    O1[(i0 + r) * HID + h] = acc1[r];
    O2[(i0 + r) * HID + h] = acc2[r];
  }
}

// ---------------------------------------------------------------------------
// Kernel 2: prep. U_i = PA[i]+PC[i-1]+PE[i+1], V_j = PB[j]+PD[j+1]+PF[j-1].
// Writes: Uf (row-major U), Vt (h-grouped transpose: float4 {V[4h..4h+3][j]}
// at Vt4[(h>>2)*NN + j]), bf16 copies for MFMA, rowstat=[sU,sU2,sV,sV2].
// ---------------------------------------------------------------------------
__global__ __launch_bounds__(256) void prep_kernel(
    const float* __restrict__ P,
    float* __restrict__ Uf, float* __restrict__ Vt,
    unsigned short* __restrict__ Ubf, unsigned short* __restrict__ Vbf,
    float* __restrict__ rowstat)
{
  const int r = blockIdx.x, h = threadIdx.x;
  const float* __restrict__ PA = P;
  const float* __restrict__ PC = P + 1 * PSTRIDE;
  const float* __restrict__ PE = P + 2 * PSTRIDE;
  const float* __restrict__ PB = P + 3 * PSTRIDE;
  const float* __restrict__ PD = P + 4 * PSTRIDE;
  const float* __restrict__ PF = P + 5 * PSTRIDE;

  float u = PA[r * HID + h] + PC[(r - 1) * HID + h] + PE[(r + 1) * HID + h];
  float v = PB[r * HID + h] + PD[(r + 1) * HID + h] + PF[(r - 1) * HID + h];
  Uf[r * HID + h] = u;
  // transposed, h-grouped-by-4 layout for coalesced thread-per-pair reads
  Vt[((h >> 2) * NN + r) * 4 + (h & 3)] = v;
  __hip_bfloat16 ub = __float2bfloat16(u), vb = __float2bfloat16(v);
  Ubf[r * HID + h] = *(unsigned short*)&ub;
  Vbf[r * HID + h] = *(unsigned short*)&vb;

  float u2 = u * u, v2 = v * v;
#pragma unroll
  for (int k = 32; k >= 1; k >>= 1) {
    u  += __shfl_xor(u,  k, 64);
    u2 += __shfl_xor(u2, k, 64);
    v  += __shfl_xor(v,  k, 64);
    v2 += __shfl_xor(v2, k, 64);
  }
  __shared__ float red[4][4];
  const int w = h >> 6;
  if ((h & 63) == 0) { red[w][0] = u; red[w][1] = u2; red[w][2] = v; red[w][3] = v2; }
  __syncthreads();
  if (h < 4)
    rowstat[h * NN + r] = red[0][h] + red[1][h] + red[2][h] + red[3][h];
}

// ---------------------------------------------------------------------------
// Kernel 3: Cross[i,j] = sum_h U[i,h]*V[j,h] via bf16 MFMA 16x16x32.
// ---------------------------------------------------------------------------
__global__ __launch_bounds__(256) void cross_kernel(
    const unsigned short* __restrict__ Ubf,
    const unsigned short* __restrict__ Vbf,
    float* __restrict__ Cross)
{
  const int wave = threadIdx.x >> 6, lane = threadIdx.x & 63;
  const int t  = blockIdx.x * 4 + wave;
  const int ti = t >> 5, tj = t & 31;
  const int i0 = ti * 16, j0 = tj * 16;
  const int rc = lane & 15, kb = (lane >> 4) * 8;

  f32x4 acc = {0.f, 0.f, 0.f, 0.f};
#pragma unroll
  for (int k = 0; k < HID; k += 32) {
    bf16x8 a = *(const bf16x8*)(Ubf + (size_t)(i0 + rc) * HID + k + kb);
    bf16x8 b = *(const bf16x8*)(Vbf + (size_t)(j0 + rc) * HID + k + kb);
    acc = __builtin_amdgcn_mfma_f32_16x16x32_bf16(a, b, acc, 0, 0, 0);
  }
  const int orow = (lane >> 4) * 4, ocol = lane & 15;
#pragma unroll
  for (int r = 0; r < 4; r++)
    Cross[(size_t)(i0 + orow + r) * NN + j0 + ocol] = acc[r];
}

__device__ __forceinline__ float celu1(float x) {
  float e = __expf(x) - 1.f;
  return x > 0.f ? x : e;
}

// ---------------------------------------------------------------------------
// Kernel 4: pair epilogue.
// Blocks [0, NB_BORDER): 2044 border pairs, 2 pairs/wave (overlap interior).
// Blocks [NB_BORDER, +1020): THREAD-PER-PAIR interior. Block = (row i, half
// of j-range); thread jj = half*256+tid; loop h=0..255 with:
//   - Vt float4 load: 4 h's per dwordx4, lanes coalesced (L2-resident)
//   - K4s[h] = {gamma,beta,W2,U_i[h]} staged in 4KB LDS, broadcast b128 reads
//   - mu/rs per-thread scalars from rowstat+Cross; NO cross-lane ops at all.
// ---------------------------------------------------------------------------
__global__ __launch_bounds__(256) void pair_kernel(
    const float* __restrict__ P,
    const float* __restrict__ Uf, const float* __restrict__ Vt,
    const float* __restrict__ Cross, const float* __restrict__ rowstat,
    const float* __restrict__ gamma, const float* __restrict__ beta,
    const float* __restrict__ W2, const float* __restrict__ b2,
    float* __restrict__ out)
{
  const int wave = threadIdx.x >> 6, lane = threadIdx.x & 63;
  const float b2s = b2[0];

  if (blockIdx.x >= NB_BORDER) {
    const int bx = blockIdx.x - NB_BORDER;        // 0..1019
    const int i  = 1 + (bx >> 1);                 // 1..510
    const int jj = ((bx & 1) << 8) + threadIdx.x; // 0..511
    const int j  = jj < 1 ? 1 : (jj > 510 ? 510 : jj);

    __shared__ float4 K4s[HID];
    K4s[threadIdx.x] = make_float4(gamma[threadIdx.x], beta[threadIdx.x],
                                   W2[threadIdx.x], Uf[i * HID + threadIdx.x]);
    __syncthreads();

    const float mu  = (rowstat[0 * NN + i] + rowstat[2 * NN + j]) * (1.f / HID);
    const float tq  = fmaf(2.f, Cross[i * NN + j],
                           rowstat[1 * NN + i] + rowstat[3 * NN + j]) * (1.f / HID);
    const float rs  = rsqrtf(tq - mu * mu + 1e-5f);
    const float mrs = -mu * rs;

    float racc0 = 0.f, racc1 = 0.f;
    const float4* __restrict__ Vp = (const float4*)Vt;   // [hb*NN + j]
#pragma unroll 4
    for (int hb = 0; hb < H4; hb++) {
      const float4 v4 = Vp[hb * NN + j];
      const float vv[4] = {v4.x, v4.y, v4.z, v4.w};
#pragma unroll
      for (int q = 0; q < 4; q++) {
        const float4 K = K4s[hb * 4 + q];
        const float s = vv[q] + K.w;
        const float n = fmaf(fmaf(s, rs, mrs), K.x, K.y);
        const float c = celu1(n);
        if (q & 1) racc1 = fmaf(c, K.z, racc1);
        else       racc0 = fmaf(c, K.z, racc0);
      }
    }
    if (jj >= 1 && jj <= 510)
      out[i * NN + jj] = racc0 + racc1 + b2s;
  } else {
    // ---- border: 2044 pairs spread over 1024 waves (2 pairs each)
    const int gw = blockIdx.x * 4 + wave;              // 0..1023
    const float4* P4 = (const float4*)P;
    const float4* PA = P4 + 0 * (PSTRIDE / 4);
    const float4* PC = P4 + 1 * (PSTRIDE / 4);
    const float4* PE = P4 + 2 * (PSTRIDE / 4);
    const float4* PB = P4 + 3 * (PSTRIDE / 4);
    const float4* PD = P4 + 4 * (PSTRIDE / 4);
    const float4* PF = P4 + 5 * (PSTRIDE / 4);
    const float4 g  = ((const float4*)gamma)[lane];
    const float4 be = ((const float4*)beta)[lane];
    const float4 w2 = ((const float4*)W2)[lane];

#pragma unroll
    for (int tt = 0; tt < 2; tt++) {
      const int p = gw * 2 + tt;
      if (p >= 2044) break;
      int i, j;
      if      (p < 512)  { i = 0;        j = p;        }
      else if (p < 1024) { i = 511;      j = p - 512;  }
      else if (p < 1534) { i = p - 1023; j = 0;        }
      else               { i = p - 1533; j = 511;      }

      const float4 a  = PA[i * H4 + lane];
      const float4 cu = PC[(i - 1) * H4 + lane];
      const float4 ed = PE[(i + 1) * H4 + lane];
      const float4 b  = PB[j * H4 + lane];
      const float4 du = PD[(j + 1) * H4 + lane];
      const float4 fd = PF[(j - 1) * H4 + lane];
      const float mu_m = (i >= 1 && j <= NN - 2) ? 1.f : 0.f;
      const float md_m = (i <= NN - 2 && j >= 1) ? 1.f : 0.f;

      float s0 = fmaf(md_m, ed.x + fd.x, fmaf(mu_m, cu.x + du.x, a.x + b.x));
      float s1 = fmaf(md_m, ed.y + fd.y, fmaf(mu_m, cu.y + du.y, a.y + b.y));
      float s2 = fmaf(md_m, ed.z + fd.z, fmaf(mu_m, cu.z + du.z, a.z + b.z));
      float s3 = fmaf(md_m, ed.w + fd.w, fmaf(mu_m, cu.w + du.w, a.w + b.w));

      float sum = (s0 + s1) + (s2 + s3);
      float ssq = fmaf(s0, s0, fmaf(s1, s1, fmaf(s2, s2, s3 * s3)));
#pragma unroll
      for (int off = 32; off >= 1; off >>= 1) {
        sum += __shfl_xor(sum, off, 64);
        ssq += __shfl_xor(ssq, off, 64);
      }
      const float mu  = sum * (1.f / HID);
      const float var = fmaf(ssq, 1.f / HID, -mu * mu);
      const float rs  = rsqrtf(var + 1e-5f);
      const float mrs = -mu * rs;

      auto nrm = [&](float s, float G, float Bt) {
        return fmaf(fmaf(s, rs, mrs), G, Bt);
      };
      float racc = fmaf(celu1(nrm(s0, g.x, be.x)), w2.x,
                   fmaf(celu1(nrm(s1, g.y, be.y)), w2.y,
                   fmaf(celu1(nrm(s2, g.z, be.z)), w2.z,
                        celu1(nrm(s3, g.w, be.w)) * w2.w)));
#pragma unroll
      for (int off = 32; off >= 1; off >>= 1)
        racc += __shfl_xor(racc, off, 64);
      if (lane == 0) out[i * NN + j] = racc + b2s;
    }
  }
}

extern "C" void kernel_launch(void* const* d_in, const int* in_sizes, int n_in,
                              void* d_out, int out_size, void* d_ws, size_t ws_size,
                              hipStream_t stream)
{
  const float* xl    = (const float*)d_in[0];
  const float* xr    = (const float*)d_in[1];
  const float* W1    = (const float*)d_in[2];
  const float* b1    = (const float*)d_in[3];
  const float* gamma = (const float*)d_in[4];
  const float* beta  = (const float*)d_in[5];
  const float* W2    = (const float*)d_in[6];
  const float* b2    = (const float*)d_in[7];
  float* out = (float*)d_out;

  float* P     = (float*)d_ws;                       // 3 MB
  float* Uf    = P + 6 * PSTRIDE;                    // 0.5 MB
  float* Vt    = Uf + NN * HID;                      // 0.5 MB (transposed V)
  float* Cross = Vt + NN * HID;                      // 1 MB
  unsigned short* Ubf = (unsigned short*)(Cross + NN * NN);
  unsigned short* Vbf = Ubf + NN * HID;
  float* rowstat = (float*)(Vbf + NN * HID);

  proj_kernel<<<dim3(NN / PROWS, 2), 256, 0, stream>>>(xl, xr, W1, b1, P);
  prep_kernel<<<NN, 256, 0, stream>>>(P, Uf, Vt, Ubf, Vbf, rowstat);
  cross_kernel<<<256, 256, 0, stream>>>(Ubf, Vbf, Cross);
  pair_kernel<<<NB_BORDER + 1020, 256, 0, stream>>>(P, Uf, Vt, Cross, rowstat,
                                                    gamma, beta, W2, b2, out);
}

// Round 7
// 107.853 us; speedup vs baseline: 1.3693x; 1.0025x over previous
//
#include <hip/hip_runtime.h>
#include <hip/hip_bf16.h>

#define NN  512
#define CC  64
#define HID 256
#define H4  (HID/4)
#define PSTRIDE (NN*HID)
#define PROWS 4                  // 4 rows/block: halves W1 L2 re-read traffic
#define NB_BORDER 256            // border blocks, dispatched first

typedef short  bf16x8 __attribute__((ext_vector_type(8)));
typedef float  f32x4  __attribute__((ext_vector_type(4)));

// ---------------------------------------------------------------------------
// Kernel 1: 6 small projections. P slots: [PA,PC,PE,PB,PD,PF], b1 in PA.
// PROWS=4 -> 128x2 blocks; W1 L2 traffic 50 MB (was 100 MB at PROWS=2).
// ---------------------------------------------------------------------------
__global__ __launch_bounds__(256) void proj_kernel(
    const float* __restrict__ xl, const float* __restrict__ xr,
    const float* __restrict__ W1, const float* __restrict__ b1,
    float* __restrict__ P)
{
  const int side = blockIdx.y;
  const int i0   = blockIdx.x * PROWS;
  const int h    = threadIdx.x;
  const float* __restrict__ x = side ? xr : xl;

  __shared__ float xs[PROWS][CC];
  // PROWS*CC == 256 == blockDim.x
  xs[threadIdx.x >> 6][threadIdx.x & 63] = x[i0 * CC + threadIdx.x];
  __syncthreads();

  float acc0[PROWS], acc1[PROWS], acc2[PROWS];
#pragma unroll
  for (int r = 0; r < PROWS; r++) { acc0[r] = 0.f; acc1[r] = 0.f; acc2[r] = 0.f; }

  const int base = side ? CC : 0;
  const float* __restrict__ w0p = W1 + (base      ) * HID + h;
  const float* __restrict__ w1p = W1 + (base + 128) * HID + h;
  const float* __restrict__ w2p = W1 + (base + 256) * HID + h;
#pragma unroll 8
  for (int c = 0; c < CC; c++) {
    float w0 = w0p[c * HID];
    float w1 = w1p[c * HID];
    float w2 = w2p[c * HID];
#pragma unroll
    for (int r = 0; r < PROWS; r++) {
      float xv = xs[r][c];
      acc0[r] = fmaf(xv, w0, acc0[r]);
      acc1[r] = fmaf(xv, w1, acc1[r]);
      acc2[r] = fmaf(xv, w2, acc2[r]);
    }
  }

  float* __restrict__ O0 = P + (side ? 3 : 0) * PSTRIDE;
  float* __restrict__ O1 = P + (side ? 4 : 1) * PSTRIDE;
  float* __restrict__ O2 = P + (side ? 5 : 2) * PSTRIDE;
  const float bb = side ? 0.f : b1[h];
#pragma unroll
  for (int r = 0; r < PROWS; r++) {
    O0[(i0 + r) * HID + h] = acc0[r] + bb;
    O1[(i0 + r) * HID + h] = acc1[r];
    O2[(i0 + r) * HID + h] = acc2[r];
  }
}

// ---------------------------------------------------------------------------
// Kernel 2: prep. U_i = PA[i]+PC[i-1]+PE[i+1], V_j = PB[j]+PD[j+1]+PF[j-1].
// Writes: Uf (row-major U), Vt (h-grouped transpose: float4 {V[4h..4h+3][j]}
// at Vt4[(h>>2)*NN + j]), bf16 copies for MFMA, rowstat=[sU,sU2,sV,sV2].
// ---------------------------------------------------------------------------
__global__ __launch_bounds__(256) void prep_kernel(
    const float* __restrict__ P,
    float* __restrict__ Uf, float* __restrict__ Vt,
    unsigned short* __restrict__ Ubf, unsigned short* __restrict__ Vbf,
    float* __restrict__ rowstat)
{
  const int r = blockIdx.x, h = threadIdx.x;
  const float* __restrict__ PA = P;
  const float* __restrict__ PC = P + 1 * PSTRIDE;
  const float* __restrict__ PE = P + 2 * PSTRIDE;
  const float* __restrict__ PB = P + 3 * PSTRIDE;
  const float* __restrict__ PD = P + 4 * PSTRIDE;
  const float* __restrict__ PF = P + 5 * PSTRIDE;

  float u = PA[r * HID + h] + PC[(r - 1) * HID + h] + PE[(r + 1) * HID + h];
  float v = PB[r * HID + h] + PD[(r + 1) * HID + h] + PF[(r - 1) * HID + h];
  Uf[r * HID + h] = u;
  Vt[((h >> 2) * NN + r) * 4 + (h & 3)] = v;
  __hip_bfloat16 ub = __float2bfloat16(u), vb = __float2bfloat16(v);
  Ubf[r * HID + h] = *(unsigned short*)&ub;
  Vbf[r * HID + h] = *(unsigned short*)&vb;

  float u2 = u * u, v2 = v * v;
#pragma unroll
  for (int k = 32; k >= 1; k >>= 1) {
    u  += __shfl_xor(u,  k, 64);
    u2 += __shfl_xor(u2, k, 64);
    v  += __shfl_xor(v,  k, 64);
    v2 += __shfl_xor(v2, k, 64);
  }
  __shared__ float red[4][4];
  const int w = h >> 6;
  if ((h & 63) == 0) { red[w][0] = u; red[w][1] = u2; red[w][2] = v; red[w][3] = v2; }
  __syncthreads();
  if (h < 4)
    rowstat[h * NN + r] = red[0][h] + red[1][h] + red[2][h] + red[3][h];
}

// ---------------------------------------------------------------------------
// Kernel 3: Cross[i,j] = sum_h U[i,h]*V[j,h] via bf16 MFMA 16x16x32.
// ---------------------------------------------------------------------------
__global__ __launch_bounds__(256) void cross_kernel(
    const unsigned short* __restrict__ Ubf,
    const unsigned short* __restrict__ Vbf,
    float* __restrict__ Cross)
{
  const int wave = threadIdx.x >> 6, lane = threadIdx.x & 63;
  const int t  = blockIdx.x * 4 + wave;
  const int ti = t >> 5, tj = t & 31;
  const int i0 = ti * 16, j0 = tj * 16;
  const int rc = lane & 15, kb = (lane >> 4) * 8;

  f32x4 acc = {0.f, 0.f, 0.f, 0.f};
#pragma unroll
  for (int k = 0; k < HID; k += 32) {
    bf16x8 a = *(const bf16x8*)(Ubf + (size_t)(i0 + rc) * HID + k + kb);
    bf16x8 b = *(const bf16x8*)(Vbf + (size_t)(j0 + rc) * HID + k + kb);
    acc = __builtin_amdgcn_mfma_f32_16x16x32_bf16(a, b, acc, 0, 0, 0);
  }
  const int orow = (lane >> 4) * 4, ocol = lane & 15;
#pragma unroll
  for (int r = 0; r < 4; r++)
    Cross[(size_t)(i0 + orow + r) * NN + j0 + ocol] = acc[r];
}

__device__ __forceinline__ float celu1(float x) {
  float e = __expf(x) - 1.f;
  return x > 0.f ? x : e;
}

// ---------------------------------------------------------------------------
// Kernel 4: pair epilogue (unchanged structure from R6; thread-per-pair
// interior with precomputed LN stats, border pairs in early blocks).
// ---------------------------------------------------------------------------
__global__ __launch_bounds__(256) void pair_kernel(
    const float* __restrict__ P,
    const float* __restrict__ Uf, const float* __restrict__ Vt,
    const float* __restrict__ Cross, const float* __restrict__ rowstat,
    const float* __restrict__ gamma, const float* __restrict__ beta,
    const float* __restrict__ W2, const float* __restrict__ b2,
    float* __restrict__ out)
{
  const int wave = threadIdx.x >> 6, lane = threadIdx.x & 63;
  const float b2s = b2[0];

  if (blockIdx.x >= NB_BORDER) {
    const int bx = blockIdx.x - NB_BORDER;        // 0..1019
    const int i  = 1 + (bx >> 1);                 // 1..510
    const int jj = ((bx & 1) << 8) + threadIdx.x; // 0..511
    const int j  = jj < 1 ? 1 : (jj > 510 ? 510 : jj);

    __shared__ float4 K4s[HID];
    K4s[threadIdx.x] = make_float4(gamma[threadIdx.x], beta[threadIdx.x],
                                   W2[threadIdx.x], Uf[i * HID + threadIdx.x]);
    __syncthreads();

    const float mu  = (rowstat[0 * NN + i] + rowstat[2 * NN + j]) * (1.f / HID);
    const float tq  = fmaf(2.f, Cross[i * NN + j],
                           rowstat[1 * NN + i] + rowstat[3 * NN + j]) * (1.f / HID);
    const float rs  = rsqrtf(tq - mu * mu + 1e-5f);
    const float mrs = -mu * rs;

    float racc0 = 0.f, racc1 = 0.f;
    const float4* __restrict__ Vp = (const float4*)Vt;   // [hb*NN + j]
#pragma unroll 8
    for (int hb = 0; hb < H4; hb++) {
      const float4 v4 = Vp[hb * NN + j];
      {
        const float4 K = K4s[hb * 4 + 0];
        const float n = fmaf(fmaf(v4.x + K.w, rs, mrs), K.x, K.y);
        racc0 = fmaf(celu1(n), K.z, racc0);
      }
      {
        const float4 K = K4s[hb * 4 + 1];
        const float n = fmaf(fmaf(v4.y + K.w, rs, mrs), K.x, K.y);
        racc1 = fmaf(celu1(n), K.z, racc1);
      }
      {
        const float4 K = K4s[hb * 4 + 2];
        const float n = fmaf(fmaf(v4.z + K.w, rs, mrs), K.x, K.y);
        racc0 = fmaf(celu1(n), K.z, racc0);
      }
      {
        const float4 K = K4s[hb * 4 + 3];
        const float n = fmaf(fmaf(v4.w + K.w, rs, mrs), K.x, K.y);
        racc1 = fmaf(celu1(n), K.z, racc1);
      }
    }
    if (jj >= 1 && jj <= 510)
      out[i * NN + jj] = racc0 + racc1 + b2s;
  } else {
    // ---- border: 2044 pairs spread over 1024 waves (2 pairs each)
    const int gw = blockIdx.x * 4 + wave;              // 0..1023
    const float4* P4 = (const float4*)P;
    const float4* PA = P4 + 0 * (PSTRIDE / 4);
    const float4* PC = P4 + 1 * (PSTRIDE / 4);
    const float4* PE = P4 + 2 * (PSTRIDE / 4);
    const float4* PB = P4 + 3 * (PSTRIDE / 4);
    const float4* PD = P4 + 4 * (PSTRIDE / 4);
    const float4* PF = P4 + 5 * (PSTRIDE / 4);
    const float4 g  = ((const float4*)gamma)[lane];
    const float4 be = ((const float4*)beta)[lane];
    const float4 w2 = ((const float4*)W2)[lane];

#pragma unroll
    for (int tt = 0; tt < 2; tt++) {
      const int p = gw * 2 + tt;
      if (p >= 2044) break;
      int i, j;
      if      (p < 512)  { i = 0;        j = p;        }
      else if (p < 1024) { i = 511;      j = p - 512;  }
      else if (p < 1534) { i = p - 1023; j = 0;        }
      else               { i = p - 1533; j = 511;      }

      const float4 a  = PA[i * H4 + lane];
      const float4 cu = PC[(i - 1) * H4 + lane];
      const float4 ed = PE[(i + 1) * H4 + lane];
      const float4 b  = PB[j * H4 + lane];
      const float4 du = PD[(j + 1) * H4 + lane];
      const float4 fd = PF[(j - 1) * H4 + lane];
      const float mu_m = (i >= 1 && j <= NN - 2) ? 1.f : 0.f;
      const float md_m = (i <= NN - 2 && j >= 1) ? 1.f : 0.f;

      float s0 = fmaf(md_m, ed.x + fd.x, fmaf(mu_m, cu.x + du.x, a.x + b.x));
      float s1 = fmaf(md_m, ed.y + fd.y, fmaf(mu_m, cu.y + du.y, a.y + b.y));
      float s2 = fmaf(md_m, ed.z + fd.z, fmaf(mu_m, cu.z + du.z, a.z + b.z));
      float s3 = fmaf(md_m, ed.w + fd.w, fmaf(mu_m, cu.w + du.w, a.w + b.w));

      float sum = (s0 + s1) + (s2 + s3);
      float ssq = fmaf(s0, s0, fmaf(s1, s1, fmaf(s2, s2, s3 * s3)));
#pragma unroll
      for (int off = 32; off >= 1; off >>= 1) {
        sum += __shfl_xor(sum, off, 64);
        ssq += __shfl_xor(ssq, off, 64);
      }
      const float mu  = sum * (1.f / HID);
      const float var = fmaf(ssq, 1.f / HID, -mu * mu);
      const float rs  = rsqrtf(var + 1e-5f);
      const float mrs = -mu * rs;

      auto nrm = [&](float s, float G, float Bt) {
        return fmaf(fmaf(s, rs, mrs), G, Bt);
      };
      float racc = fmaf(celu1(nrm(s0, g.x, be.x)), w2.x,
                   fmaf(celu1(nrm(s1, g.y, be.y)), w2.y,
                   fmaf(celu1(nrm(s2, g.z, be.z)), w2.z,
                        celu1(nrm(s3, g.w, be.w)) * w2.w)));
#pragma unroll
      for (int off = 32; off >= 1; off >>= 1)
        racc += __shfl_xor(racc, off, 64);
      if (lane == 0) out[i * NN + j] = racc + b2s;
    }
  }
}

extern "C" void kernel_launch(void* const* d_in, const int* in_sizes, int n_in,
                              void* d_out, int out_size, void* d_ws, size_t ws_size,
                              hipStream_t stream)
{
  const float* xl    = (const float*)d_in[0];
  const float* xr    = (const float*)d_in[1];
  const float* W1    = (const float*)d_in[2];
  const float* b1    = (const float*)d_in[3];
  const float* gamma = (const float*)d_in[4];
  const float* beta  = (const float*)d_in[5];
  const float* W2    = (const float*)d_in[6];
  const float* b2    = (const float*)d_in[7];
  float* out = (float*)d_out;

  float* P     = (float*)d_ws;                       // 3 MB
  float* Uf    = P + 6 * PSTRIDE;                    // 0.5 MB
  float* Vt    = Uf + NN * HID;                      // 0.5 MB (transposed V)
  float* Cross = Vt + NN * HID;                      // 1 MB
  unsigned short* Ubf = (unsigned short*)(Cross + NN * NN);
  unsigned short* Vbf = Ubf + NN * HID;
  float* rowstat = (float*)(Vbf + NN * HID);

  proj_kernel<<<dim3(NN / PROWS, 2), 256, 0, stream>>>(xl, xr, W1, b1, P);
  prep_kernel<<<NN, 256, 0, stream>>>(P, Uf, Vt, Ubf, Vbf, rowstat);
  cross_kernel<<<256, 256, 0, stream>>>(Ubf, Vbf, Cross);
  pair_kernel<<<NB_BORDER + 1020, 256, 0, stream>>>(P, Uf, Vt, Cross, rowstat,
                                                    gamma, beta, W2, b2, out);
}